// Round 3
// baseline (40.413 us; speedup 1.0000x reference)
//
#include <hip/hip_runtime.h>
#include <hip/hip_bf16.h>
#include <hip/hip_cooperative_groups.h>
#include <math.h>

namespace cg = cooperative_groups;

#define EPS 1e-9f
// 4 / pi^2
#define FOUR_OVER_PI2 0.40528473456935108578f

#define BLOCK 256

__device__ __forceinline__ float ciou_loss_elem(float4 a, float4 b,
                                                int mval, float bn)
{
    float x1a = a.x, y1a = a.y, x2a = a.z, y2a = a.w;
    float x1b = b.x, y1b = b.y, x2b = b.z, y2b = b.w;

    float xmin = fmaxf(x1a, x1b);
    float ymin = fmaxf(y1a, y1b);
    float xmax = fminf(x2a, x2b);
    float ymax = fminf(y2a, y2b);

    float iw = fmaxf(xmax - xmin, 0.0f);
    float ih = fmaxf(ymax - ymin, 0.0f);
    float inter = iw * ih;

    float wa = x2a - x1a, ha = y2a - y1a;
    float wb = x2b - x1b, hb = y2b - y1b;

    float area_a = wa * ha;
    float area_b = wb * hb;
    float uni = area_a + area_b - inter;
    float iou = inter / (uni + EPS);

    float cx = (x1a + x2a - x1b - x2b) * 0.5f;
    float cy = (y1a + y2a - y1b - y2b) * 0.5f;
    float cent2 = cx * cx + cy * cy;

    float cw = fmaxf(x2a, x2b) - fminf(x1a, x1b);
    float ch = fmaxf(y2a, y2b) - fminf(y1a, y1b);
    float diag2 = cw * cw + ch * ch;

    float diou = iou - cent2 / (diag2 + EPS);

    float at = atanf(wa / (ha + EPS)) - atanf(wb / (hb + EPS));
    float v = FOUR_OVER_PI2 * at * at;
    float alpha = v / (v - iou + 1.0f + EPS);
    float ciou = diou - alpha * v;

    float m = (mval != 0) ? 1.0f : 0.0f;
    return (1.0f - ciou) * m * bn;
}

// Single fused cooperative kernel:
//   phase 1: each block computes a partial sum (4 consecutive elems/thread,
//            vectorized int4/float4 mask+norm loads) -> d_ws[blockIdx]
//   grid.sync()
//   phase 2: block 0 reduces the partials and writes the final scalar.
__global__ __launch_bounds__(BLOCK) void ciou_fused_kernel(
    const float4* __restrict__ pb,
    const float4* __restrict__ tb,
    const int4* __restrict__ mask4,
    const float4* __restrict__ bn4,
    const float* __restrict__ cls_norm,
    float* __restrict__ out,
    float* __restrict__ partials,
    int ngroups,   // n/4
    int nparts)    // gridDim.x
{
    int g = blockIdx.x * BLOCK + threadIdx.x;

    float local = 0.0f;
    if (g < ngroups) {
        int4   mv = mask4[g];
        float4 bn = bn4[g];
        int base = g * 4;
        local  = ciou_loss_elem(pb[base + 0], tb[base + 0], mv.x, bn.x);
        local += ciou_loss_elem(pb[base + 1], tb[base + 1], mv.y, bn.y);
        local += ciou_loss_elem(pb[base + 2], tb[base + 2], mv.z, bn.z);
        local += ciou_loss_elem(pb[base + 3], tb[base + 3], mv.w, bn.w);
    }

    // wave-level reduction (wave = 64 lanes on CDNA)
    #pragma unroll
    for (int off = 32; off > 0; off >>= 1)
        local += __shfl_down(local, off, 64);

    __shared__ float smem[BLOCK / 64];
    int lane = threadIdx.x & 63;
    int wid  = threadIdx.x >> 6;
    if (lane == 0) smem[wid] = local;
    __syncthreads();

    if (threadIdx.x == 0) {
        partials[blockIdx.x] = smem[0] + smem[1] + smem[2] + smem[3];
    }

    cg::this_grid().sync();

    if (blockIdx.x == 0) {
        float v = (threadIdx.x < nparts) ? partials[threadIdx.x] : 0.0f;

        #pragma unroll
        for (int off = 32; off > 0; off >>= 1)
            v += __shfl_down(v, off, 64);

        __shared__ float smem2[BLOCK / 64];
        if (lane == 0) smem2[wid] = v;
        __syncthreads();

        if (threadIdx.x == 0) {
            float s = smem2[0] + smem2[1] + smem2[2] + smem2[3];
            out[0] = s / cls_norm[0];
        }
    }
}

extern "C" void kernel_launch(void* const* d_in, const int* in_sizes, int n_in,
                              void* d_out, int out_size, void* d_ws, size_t ws_size,
                              hipStream_t stream) {
    const float4* pb       = (const float4*)d_in[0];
    const float4* tb       = (const float4*)d_in[1];
    const int4*   mask4    = (const int4*)d_in[2];
    const float4* bn4      = (const float4*)d_in[3];
    const float*  cls_norm = (const float*)d_in[4];
    float* out      = (float*)d_out;
    float* partials = (float*)d_ws;

    int n = in_sizes[3];            // box_norm has N elements (divisible by 4)
    int ngroups = n / 4;            // 33600
    int grid = (ngroups + BLOCK - 1) / BLOCK;   // 132 blocks <= 256 CUs

    void* args[] = { &pb, &tb, &mask4, &bn4, &cls_norm, &out, &partials,
                     &ngroups, &grid };
    hipLaunchCooperativeKernel((const void*)ciou_fused_kernel,
                               dim3(grid), dim3(BLOCK), args, 0, stream);
}

// Round 4
// 12.212 us; speedup vs baseline: 3.3091x; 3.3091x over previous
//
#include <hip/hip_runtime.h>
#include <hip/hip_bf16.h>
#include <math.h>

#define EPS 1e-9f
// 4 / pi^2
#define FOUR_OVER_PI2 0.40528473456935108578f

#define BLOCK 256

__device__ __forceinline__ float ciou_loss_elem(float4 a, float4 b,
                                                int mval, float bn)
{
    float x1a = a.x, y1a = a.y, x2a = a.z, y2a = a.w;
    float x1b = b.x, y1b = b.y, x2b = b.z, y2b = b.w;

    float xmin = fmaxf(x1a, x1b);
    float ymin = fmaxf(y1a, y1b);
    float xmax = fminf(x2a, x2b);
    float ymax = fminf(y2a, y2b);

    float iw = fmaxf(xmax - xmin, 0.0f);
    float ih = fmaxf(ymax - ymin, 0.0f);
    float inter = iw * ih;

    float wa = x2a - x1a, ha = y2a - y1a;
    float wb = x2b - x1b, hb = y2b - y1b;

    float area_a = wa * ha;
    float area_b = wb * hb;
    float uni = area_a + area_b - inter;
    float iou = inter / (uni + EPS);

    float cx = (x1a + x2a - x1b - x2b) * 0.5f;
    float cy = (y1a + y2a - y1b - y2b) * 0.5f;
    float cent2 = cx * cx + cy * cy;

    float cw = fmaxf(x2a, x2b) - fminf(x1a, x1b);
    float ch = fmaxf(y2a, y2b) - fminf(y1a, y1b);
    float diag2 = cw * cw + ch * ch;

    float diou = iou - cent2 / (diag2 + EPS);

    float at = atanf(wa / (ha + EPS)) - atanf(wb / (hb + EPS));
    float v = FOUR_OVER_PI2 * at * at;
    float alpha = v / (v - iou + 1.0f + EPS);
    float ciou = diou - alpha * v;

    float m = (mval != 0) ? 1.0f : 0.0f;
    return (1.0f - ciou) * m * bn;
}

// Stage 1: per-block partial sums into d_ws (no atomics, no contention).
// Each thread handles 4 CONSECUTIVE elements -> mask/box_norm load as
// int4/float4 (16 B/lane), boxes as 4x float4 over a contiguous 64 B span.
__global__ __launch_bounds__(BLOCK) void ciou_partial_kernel(
    const float4* __restrict__ pb,
    const float4* __restrict__ tb,
    const int4* __restrict__ mask4,
    const float4* __restrict__ bn4,
    float* __restrict__ partials,
    int ngroups)
{
    int g = blockIdx.x * BLOCK + threadIdx.x;

    float local = 0.0f;
    if (g < ngroups) {
        int4   mv = mask4[g];
        float4 bn = bn4[g];
        int base = g * 4;
        local  = ciou_loss_elem(pb[base + 0], tb[base + 0], mv.x, bn.x);
        local += ciou_loss_elem(pb[base + 1], tb[base + 1], mv.y, bn.y);
        local += ciou_loss_elem(pb[base + 2], tb[base + 2], mv.z, bn.z);
        local += ciou_loss_elem(pb[base + 3], tb[base + 3], mv.w, bn.w);
    }

    // wave-level reduction (wave = 64 lanes on CDNA)
    #pragma unroll
    for (int off = 32; off > 0; off >>= 1)
        local += __shfl_down(local, off, 64);

    __shared__ float smem[BLOCK / 64];
    int lane = threadIdx.x & 63;
    int wid  = threadIdx.x >> 6;
    if (lane == 0) smem[wid] = local;
    __syncthreads();

    if (threadIdx.x == 0) {
        partials[blockIdx.x] = smem[0] + smem[1] + smem[2] + smem[3];
    }
}

// Stage 2: one block reduces the partials and writes the final scalar.
__global__ __launch_bounds__(BLOCK) void ciou_final_kernel(
    const float* __restrict__ partials,
    const float* __restrict__ cls_norm,
    float* __restrict__ out,
    int nparts)
{
    float local = (threadIdx.x < nparts) ? partials[threadIdx.x] : 0.0f;

    #pragma unroll
    for (int off = 32; off > 0; off >>= 1)
        local += __shfl_down(local, off, 64);

    __shared__ float smem[BLOCK / 64];
    int lane = threadIdx.x & 63;
    int wid  = threadIdx.x >> 6;
    if (lane == 0) smem[wid] = local;
    __syncthreads();

    if (threadIdx.x == 0) {
        float s = smem[0] + smem[1] + smem[2] + smem[3];
        out[0] = s / cls_norm[0];   // plain store — no zeroing needed
    }
}

extern "C" void kernel_launch(void* const* d_in, const int* in_sizes, int n_in,
                              void* d_out, int out_size, void* d_ws, size_t ws_size,
                              hipStream_t stream) {
    const float4* pb       = (const float4*)d_in[0];
    const float4* tb       = (const float4*)d_in[1];
    const int4*   mask4    = (const int4*)d_in[2];
    const float4* bn4      = (const float4*)d_in[3];
    const float*  cls_norm = (const float*)d_in[4];
    float* out      = (float*)d_out;
    float* partials = (float*)d_ws;

    int n = in_sizes[3];            // box_norm has N elements (divisible by 4)
    int ngroups = n / 4;            // 33600
    int grid = (ngroups + BLOCK - 1) / BLOCK;   // 132 blocks <= 256 CUs

    ciou_partial_kernel<<<grid, BLOCK, 0, stream>>>(pb, tb, mask4, bn4, partials, ngroups);
    ciou_final_kernel<<<1, BLOCK, 0, stream>>>(partials, cls_norm, out, grid);
}